// Round 1
// 343.287 us; speedup vs baseline: 1.0726x; 1.0726x over previous
//
#include <hip/hip_runtime.h>
#include <hip/hip_bf16.h>

typedef __bf16 bf16_t;
typedef __attribute__((ext_vector_type(8))) __bf16 bf16x8;
typedef __attribute__((ext_vector_type(4))) float f32x4;

// ------- pack B[K,N] f32 -> bf16 MFMA fragments ---------------------------
__device__ inline void packB_one(const float* __restrict__ B, bf16_t* __restrict__ Bp,
                                 int N, int idx) {
    int j    = idx & 7;
    int lane = (idx >> 3) & 63;
    int st   = idx >> 9;
    int nt   = N >> 4;
    int s = st / nt, t = st - s * nt;
    int k = s * 32 + (lane >> 4) * 8 + j;
    int n = t * 16 + (lane & 15);
    Bp[idx] = (bf16_t)B[(size_t)k * N + n];
}

// ------- fused front-end: pack both weights + degree count ---------------
// blocks [0,144): pack;  blocks [144, ...): degree histogram, 4 edges/thread
__global__ __launch_bounds__(256) void k_front(
        const float* __restrict__ W1, bf16_t* __restrict__ Bp1,
        const float* __restrict__ W2, bf16_t* __restrict__ Bp2,
        const int* __restrict__ dst, int* __restrict__ deg, int E) {
    int b = blockIdx.x, t = threadIdx.x;
    const int PACK_BLOCKS = (32768 + 4096) / 256;   // 144
    if (b < PACK_BLOCKS) {
        int idx = b * 256 + t;
        if (idx < 32768) packB_one(W1, Bp1, 128, idx);
        else             packB_one(W2, Bp2, 32, idx - 32768);
        return;
    }
    int i = (b - PACK_BLOCKS) * 1024 + t * 4;
    if (i + 4 <= E) {
        int4 v = *(const int4*)(dst + i);
        atomicAdd(&deg[v.x], 1); atomicAdd(&deg[v.y], 1);
        atomicAdd(&deg[v.z], 1); atomicAdd(&deg[v.w], 1);
    } else {
#pragma unroll
        for (int j = 0; j < 4; ++j)
            if (i + j < E) atomicAdd(&deg[dst[i + j]], 1);
    }
}

// ---------------- dinv + scan phase 1 (fused) -----------------------------
__global__ __launch_bounds__(256) void k_dinv_scan1(const int* __restrict__ deg,
                                                    float* __restrict__ dinv,
                                                    int* __restrict__ bsum, int n) {
    __shared__ int red[256];
    int b = blockIdx.x, t = threadIdx.x;
    int base = b * 1024 + t * 4;
    int s = 0;
#pragma unroll
    for (int j = 0; j < 4; ++j) {
        int i = base + j;
        if (i < n) { int d = deg[i]; s += d; dinv[i] = rsqrtf((float)(d + 1)); }
    }
    red[t] = s;
    __syncthreads();
    for (int d = 128; d > 0; d >>= 1) {
        if (t < d) red[t] += red[t + d];
        __syncthreads();
    }
    if (t == 0) bsum[b] = red[0];
}

// phase 2: single block scans <=256 block sums (exclusive), writes rowPtr[n]=E
__global__ __launch_bounds__(256) void k_scan2(int* __restrict__ bsum, int nb,
                                               int* __restrict__ rowPtr, int n) {
    __shared__ int s[256];
    int t = threadIdx.x;
    int v = (t < nb) ? bsum[t] : 0;
    s[t] = v;
    __syncthreads();
    for (int d = 1; d < 256; d <<= 1) {   // Hillis-Steele inclusive
        int u = (t >= d) ? s[t - d] : 0;
        __syncthreads();
        s[t] += u;
        __syncthreads();
    }
    if (t < nb) bsum[t] = s[t] - v;       // exclusive block offset
    if (t == 255) rowPtr[n] = s[255];     // total = E
}

// phase 3: block-local exclusive scan + block offset -> rowPtr AND cursor
// (cursor = absolute write position; scatter then needs a single atomicAdd)
__global__ __launch_bounds__(256) void k_scan3(const int* __restrict__ deg,
                                               const int* __restrict__ bsum,
                                               int* __restrict__ rowPtr,
                                               int* __restrict__ cursor, int n) {
    __shared__ int red[256];
    int b = blockIdx.x, t = threadIdx.x;
    int base = b * 1024 + t * 4;
    int v[4]; int s = 0;
#pragma unroll
    for (int j = 0; j < 4; ++j) { int i = base + j; v[j] = (i < n) ? deg[i] : 0; s += v[j]; }
    red[t] = s;
    __syncthreads();
    for (int d = 1; d < 256; d <<= 1) {
        int u = (t >= d) ? red[t - d] : 0;
        __syncthreads();
        red[t] += u;
        __syncthreads();
    }
    int run = bsum[b] + red[t] - s;
#pragma unroll
    for (int j = 0; j < 4; ++j) {
        int i = base + j;
        if (i < n) { rowPtr[i] = run; cursor[i] = run; run += v[j]; }
    }
}

// ------- fused: layer-1 GEMM + edge scatter (independent work) ------------
// blocks [0, gemmBlocks): XW1 = bf16(feat @ W1), wave = 16 rows x 128 cols
// blocks [gemmBlocks, ...): scatter edges into CSR, payload = {src, nrm}
template <int KSTEPS, int NTILES>
__global__ __launch_bounds__(256) void k_gemm_scatter(
        const float* __restrict__ A, const bf16_t* __restrict__ Bp,
        bf16_t* __restrict__ C, int M, int gemmBlocks,
        const int* __restrict__ src, const int* __restrict__ dst,
        const float* __restrict__ dinv, int* __restrict__ cursor,
        int2* __restrict__ edata, int E) {
    int b = blockIdx.x, t = threadIdx.x;
    if (b < gemmBlocks) {
        int wave = (b * 256 + t) >> 6;
        if (wave * 16 >= M) return;
        int lane = t & 63;
        int r16 = lane & 15, quad = lane >> 4;
        const int K = KSTEPS * 32, N = NTILES * 16;
        f32x4 acc[NTILES] = {};
        const float* arow = A + (size_t)(wave * 16 + r16) * K + quad * 8;
#pragma unroll
        for (int s = 0; s < KSTEPS; ++s) {
            const float* ap = arow + s * 32;
            bf16x8 a;
#pragma unroll
            for (int j = 0; j < 8; ++j) a[j] = (bf16_t)ap[j];
            const bf16_t* bp = Bp + ((size_t)(s * NTILES) * 64 + lane) * 8;
#pragma unroll
            for (int tt = 0; tt < NTILES; ++tt) {
                bf16x8 bb = *(const bf16x8*)(bp + tt * 512);
                acc[tt] = __builtin_amdgcn_mfma_f32_16x16x32_bf16(a, bb, acc[tt], 0, 0, 0);
            }
        }
#pragma unroll
        for (int tt = 0; tt < NTILES; ++tt)
#pragma unroll
            for (int r = 0; r < 4; ++r)
                C[(size_t)(wave * 16 + quad * 4 + r) * N + tt * 16 + r16] = (bf16_t)acc[tt][r];
        return;
    }
    int e = (b - gemmBlocks) * 256 + t;
    if (e >= E) return;
    int s = src[e], d = dst[e];
    int pos = atomicAdd(&cursor[d], 1);   // cursor pre-seeded with rowPtr
    int2 p; p.x = s; p.y = __float_as_int(dinv[s] * dinv[d]);
    edata[pos] = p;
}

// ------- layer-2 GEMM with packed A (bf16 H) ------------------------------
template <int KSTEPS, int NTILES>
__global__ __launch_bounds__(256) void k_gemm_pa16(
        const bf16_t* __restrict__ A, const bf16_t* __restrict__ Bp,
        bf16_t* __restrict__ C, int M) {
    int wave = (blockIdx.x * blockDim.x + threadIdx.x) >> 6;
    if (wave * 16 >= M) return;
    int lane = threadIdx.x & 63;
    int r16 = lane & 15, quad = lane >> 4;
    const int K = KSTEPS * 32, N = NTILES * 16;
    f32x4 acc[NTILES] = {};
    const bf16_t* arow = A + (size_t)(wave * 16 + r16) * K + quad * 8;
#pragma unroll
    for (int s = 0; s < KSTEPS; ++s) {
        bf16x8 a = *(const bf16x8*)(arow + s * 32);
        const bf16_t* bp = Bp + ((size_t)(s * NTILES) * 64 + lane) * 8;
#pragma unroll
        for (int t = 0; t < NTILES; ++t) {
            bf16x8 b = *(const bf16x8*)(bp + t * 512);
            acc[t] = __builtin_amdgcn_mfma_f32_16x16x32_bf16(a, b, acc[t], 0, 0, 0);
        }
    }
#pragma unroll
    for (int t = 0; t < NTILES; ++t)
#pragma unroll
        for (int r = 0; r < 4; ++r)
            C[(size_t)(wave * 16 + quad * 4 + r) * N + t * 16 + r16] = (bf16_t)acc[t][r];
}

// ------- layer-1 aggregate: 16 lanes x bf16x8, 4 parity streams, 2-unroll -
__global__ __launch_bounds__(256) void k_agg1(
        const int* __restrict__ rowPtr, const int2* __restrict__ edata,
        const bf16_t* __restrict__ XW1, const float* __restrict__ dinv,
        const float* __restrict__ b1, bf16_t* __restrict__ H, int n) {
    int wave = (blockIdx.x * blockDim.x + threadIdx.x) >> 6;
    if (wave >= n) return;
    int lane = threadIdx.x & 63;
    int fl = (lane & 15) << 3;   // 8 features
    int h  = lane >> 4;          // parity stream 0..3
    int r0 = rowPtr[wave], r1 = rowPtr[wave + 1];
    float a0[8] = {}, a1[8] = {};
    int k = r0 + h;
    for (; k + 4 < r1; k += 8) {          // 2 independent gathers in flight
        int2 e0 = edata[k], e1 = edata[k + 4];
        float w0 = __int_as_float(e0.y), w1 = __int_as_float(e1.y);
        bf16x8 x0 = *(const bf16x8*)(XW1 + ((size_t)e0.x << 7) + fl);
        bf16x8 x1 = *(const bf16x8*)(XW1 + ((size_t)e1.x << 7) + fl);
#pragma unroll
        for (int j = 0; j < 8; ++j) { a0[j] += (float)x0[j] * w0; a1[j] += (float)x1[j] * w1; }
    }
    if (k < r1) {
        int2 e0 = edata[k];
        float w0 = __int_as_float(e0.y);
        bf16x8 x0 = *(const bf16x8*)(XW1 + ((size_t)e0.x << 7) + fl);
#pragma unroll
        for (int j = 0; j < 8; ++j) a0[j] += (float)x0[j] * w0;
    }
#pragma unroll
    for (int j = 0; j < 8; ++j) {        // convergent reduction over 4 streams
        a0[j] += a1[j];
        a0[j] += __shfl_xor(a0[j], 16);
        a0[j] += __shfl_xor(a0[j], 32);
    }
    if (h == 0) {
        float d = dinv[wave], d2 = d * d;
        bf16x8 xs = *(const bf16x8*)(XW1 + ((size_t)wave << 7) + fl);
        bf16x8 hv;
#pragma unroll
        for (int j = 0; j < 8; ++j) {
            float v = a0[j] + (float)xs[j] * d2 + b1[fl + j];
            hv[j] = (bf16_t)fmaxf(v, 0.f);
        }
        *(bf16x8*)(H + ((size_t)wave << 7) + fl) = hv;
    }
}

// ------- layer-2 aggregate + log_softmax ----------------------------------
// 4 streams x 16 lanes; each lane loads 2 classes as one uint (bf16 pair
// decoded by shift -- no cvt), 2-unroll => 8 gathers in flight per wave.
__global__ __launch_bounds__(256) void k_agg2(
        const int* __restrict__ rowPtr, const int2* __restrict__ edata,
        const bf16_t* __restrict__ XW2, const float* __restrict__ dinv,
        const float* __restrict__ b2, float* __restrict__ out, int n) {
    int wave = (blockIdx.x * blockDim.x + threadIdx.x) >> 6;
    if (wave >= n) return;
    int lane = threadIdx.x & 63;
    int g = lane & 15;           // class pair: {2g, 2g+1}
    int h = lane >> 4;           // stream 0..3
    int r0 = rowPtr[wave], r1 = rowPtr[wave + 1];
    float a00 = 0.f, a01 = 0.f, a10 = 0.f, a11 = 0.f;
    int k = r0 + h;
    for (; k + 4 < r1; k += 8) {
        int2 e0 = edata[k], e1 = edata[k + 4];
        float w0 = __int_as_float(e0.y), w1 = __int_as_float(e1.y);
        unsigned p0 = *(const unsigned*)(XW2 + ((size_t)e0.x << 5) + 2 * g);
        unsigned p1 = *(const unsigned*)(XW2 + ((size_t)e1.x << 5) + 2 * g);
        a00 += __int_as_float(p0 << 16) * w0;
        a01 += __int_as_float(p0 & 0xffff0000u) * w0;
        a10 += __int_as_float(p1 << 16) * w1;
        a11 += __int_as_float(p1 & 0xffff0000u) * w1;
    }
    if (k < r1) {
        int2 e0 = edata[k];
        float w0 = __int_as_float(e0.y);
        unsigned p0 = *(const unsigned*)(XW2 + ((size_t)e0.x << 5) + 2 * g);
        a00 += __int_as_float(p0 << 16) * w0;
        a01 += __int_as_float(p0 & 0xffff0000u) * w0;
    }
    float v0 = a00 + a10, v1 = a01 + a11;
    v0 += __shfl_xor(v0, 16); v0 += __shfl_xor(v0, 32);   // combine 4 streams
    v1 += __shfl_xor(v1, 16); v1 += __shfl_xor(v1, 32);
    float d = dinv[wave], d2 = d * d;
    unsigned ps = *(const unsigned*)(XW2 + ((size_t)wave << 5) + 2 * g);
    float2 bb = *(const float2*)(b2 + 2 * g);
    v0 += __int_as_float(ps << 16) * d2 + bb.x;
    v1 += __int_as_float(ps & 0xffff0000u) * d2 + bb.y;
    float mx = fmaxf(v0, v1);
#pragma unroll
    for (int m = 8; m >= 1; m >>= 1) mx = fmaxf(mx, __shfl_xor(mx, m));
    float s = expf(v0 - mx) + expf(v1 - mx);
#pragma unroll
    for (int m = 8; m >= 1; m >>= 1) s += __shfl_xor(s, m);
    if (h == 0) {
        float ls = logf(s);
        float2 o; o.x = v0 - mx - ls; o.y = v1 - mx - ls;
        *(float2*)(out + ((size_t)wave << 5) + 2 * g) = o;
    }
}

extern "C" void kernel_launch(void* const* d_in, const int* in_sizes, int n_in,
                              void* d_out, int out_size, void* d_ws, size_t ws_size,
                              hipStream_t stream) {
    const float* feat = (const float*)d_in[0];
    const int*   eidx = (const int*)d_in[1];
    const float* W1   = (const float*)d_in[2];
    const float* b1   = (const float*)d_in[3];
    const float* W2   = (const float*)d_in[4];
    const float* b2   = (const float*)d_in[5];
    float* out = (float*)d_out;

    const int FIN = 256, HID = 128, NCLS = 32;
    const int N = in_sizes[0] / FIN;   // 100000
    const int E = in_sizes[1] / 2;     // 800000
    const int* src = eidx;
    const int* dst = eidx + E;

    // workspace carve-up (256B aligned)
    char* ws = (char*)d_ws;
    size_t o = 0;
    auto alloc = [&](size_t bytes) -> void* {
        void* p = ws + o;
        o = (o + bytes + 255) & ~(size_t)255;
        return p;
    };
    int*    deg    = (int*)   alloc((size_t)N * 4);
    int*    cursor = (int*)   alloc((size_t)N * 4);   // seeded by k_scan3
    float*  dinv   = (float*) alloc((size_t)N * 4);
    int*    rowPtr = (int*)   alloc((size_t)(N + 1) * 4);
    int*    bsum   = (int*)   alloc(256 * 4);
    bf16_t* Bp1    = (bf16_t*)alloc((size_t)(FIN / 32) * (HID / 16) * 512 * 2);
    bf16_t* Bp2    = (bf16_t*)alloc((size_t)(HID / 32) * (NCLS / 16) * 512 * 2);
    int2*   edata  = (int2*)  alloc((size_t)E * 8);        // 6.4 MB
    bf16_t* XW1    = (bf16_t*)alloc((size_t)N * HID * 2);  // 25.6 MB
    bf16_t* H      = (bf16_t*)alloc((size_t)N * HID * 2);  // 25.6 MB
    bf16_t* XW2    = XW1;   // alias: XW1 dead after k_agg1

    const int T = 256;
    const int NB = (N + 1023) >> 10;                 // 98 scan blocks (<=256)
    const int PACK_BLOCKS = (32768 + 4096) / 256;    // 144
    const int DEG_BLOCKS  = (E + 1023) / 1024;       // 782 (4 edges/thread)
    hipMemsetAsync(deg, 0, (size_t)N * 4, stream);
    k_front     <<<PACK_BLOCKS + DEG_BLOCKS, T, 0, stream>>>(W1, Bp1, W2, Bp2, dst, deg, E);
    k_dinv_scan1<<<NB, T, 0, stream>>>(deg, dinv, bsum, N);
    k_scan2     <<<1, T, 0, stream>>>(bsum, NB, rowPtr, N);
    k_scan3     <<<NB, T, 0, stream>>>(deg, bsum, rowPtr, cursor, N);

    // layer-1 GEMM fused with the (independent) edge scatter: scatter hides
    // under the GEMM's memory traffic instead of serializing after it.
    {
        int waves = (N + 15) / 16;
        int gemmBlocks = (waves * 64 + T - 1) / T;          // 1563
        int scatBlocks = (E + T - 1) / T;                   // 3125
        k_gemm_scatter<8, 8><<<gemmBlocks + scatBlocks, T, 0, stream>>>(
            feat, Bp1, XW1, N, gemmBlocks, src, dst, dinv, cursor, edata, E);
    }
    k_agg1<<<(N * 64 + T - 1) / T, T, 0, stream>>>(rowPtr, edata, XW1, dinv, b1, H, N);

    // layer 2: XW2 = bf16(H @ W2)
    {
        int waves = (N + 15) / 16;
        k_gemm_pa16<4, 2><<<(waves * 64 + T - 1) / T, T, 0, stream>>>(H, Bp2, XW2, N);
    }
    k_agg2<<<(N * 64 + T - 1) / T, T, 0, stream>>>(rowPtr, edata, XW2, dinv, b2, out, N);
}